// Round 13
// baseline (898.579 us; speedup 1.0000x reference)
//
#include <hip/hip_runtime.h>

// Problem constants: B=16, C=320, H=W=64, G=5, Cg=64
#define BATCH 16
#define CHAN  320
#define HH    64
#define WW    64
#define PLANE (HH*WW)            // 4096
#define NGRP  5
#define CG    64
#define NTOT  ((size_t)BATCH * CHAN * PLANE)
#define N4    (NTOT / 4)
#define GSBLK 2048
#define GSSTRIDE (GSBLK * 256)
#define PASSES 8

__device__ float g_em[BATCH * PLANE];
__device__ float g_w0[BATCH * PLANE];

// ---------------------------------------------------------------------------
// Kernel 1: channel-sum of edge_guidance
// ---------------------------------------------------------------------------
__global__ void k_reduce_mean(const float* __restrict__ eg)
{
    __shared__ float red[256];
    const int bid = blockIdx.x;
    const int b = bid >> 6;
    const int r = bid & 63;
    const int q   = threadIdx.x & 63;
    const int grp = threadIdx.x >> 6;

    const float* p = eg + (((size_t)b * CHAN + (size_t)grp * 80) * PLANE) + r * WW + q;
    float s = 0.f;
#pragma unroll 8
    for (int c = 0; c < 80; ++c)
        s += p[(size_t)c * PLANE];

    red[threadIdx.x] = s;
    __syncthreads();
    if (grp == 0) {
        g_em[(size_t)bid * 64 + q] = red[q] + red[q + 64] + red[q + 128] + red[q + 192];
    }
}

// ---------------------------------------------------------------------------
// Kernel 2: conv1+relu -> conv2 -> softmax -> w0
// ---------------------------------------------------------------------------
__global__ void k_conv_dir(const float* __restrict__ w1, const float* __restrict__ b1,
                           const float* __restrict__ w2, const float* __restrict__ b2)
{
    __shared__ float sem[20][20];
    __shared__ float shh[18][18];
    __shared__ float sw1[16][9];
    __shared__ float sb1[16];
    __shared__ float sw2[2][16][9];
    __shared__ float sb2[2];

    const int bid = blockIdx.x;
    const int b  = bid >> 4;
    const int t  = bid & 15;
    const int r0 = (t >> 2) * 16;
    const int q0 = (t & 3) * 16;
    const int tid = threadIdx.x;

    if (tid < 144) sw1[tid / 9][tid % 9] = w1[tid];
    if (tid < 16)  sb1[tid] = b1[tid];
    for (int i = tid; i < 288; i += 256) ((float*)sw2)[i] = w2[i];
    if (tid < 2)   sb2[tid] = b2[tid];

    const float scale = 1.0f / (float)CHAN;
    for (int i = tid; i < 400; i += 256) {
        const int lr = i / 20, lq = i % 20;
        const int r = r0 + lr - 2, q = q0 + lq - 2;
        float v = 0.f;
        if ((unsigned)r < HH && (unsigned)q < WW)
            v = g_em[((size_t)b * HH + r) * WW + q] * scale;
        sem[lr][lq] = v;
    }
    __syncthreads();

    const int lr = tid >> 4;
    const int lq = tid & 15;
    float l0 = sb2[0];
    float l1 = sb2[1];

    for (int i = 0; i < 16; ++i) {
        for (int p = tid; p < 324; p += 256) {
            const int hr = p / 18, hq = p % 18;
            const int gr = r0 - 1 + hr, gq = q0 - 1 + hq;
            float acc = 0.f;
            if ((unsigned)gr < HH && (unsigned)gq < WW) {
                acc = sb1[i];
#pragma unroll
                for (int dr = 0; dr < 3; ++dr)
#pragma unroll
                    for (int dq = 0; dq < 3; ++dq)
                        acc += sem[hr + dr][hq + dq] * sw1[i][dr * 3 + dq];
                acc = fmaxf(acc, 0.f);
            }
            shh[hr][hq] = acc;
        }
        __syncthreads();
#pragma unroll
        for (int dr = 0; dr < 3; ++dr)
#pragma unroll
            for (int dq = 0; dq < 3; ++dq) {
                const float hv = shh[lr + dr][lq + dq];
                l0 += hv * sw2[0][i][dr * 3 + dq];
                l1 += hv * sw2[1][i][dr * 3 + dq];
            }
        __syncthreads();
    }

    const float m  = fmaxf(l0, l1);
    const float e0 = expf(l0 - m);
    const float e1 = expf(l1 - m);
    const float w0v = e0 / (e0 + e1);
    g_w0[((size_t)b * HH + (r0 + lr)) * WW + (q0 + lq)] = w0v;
}

// ---------------------------------------------------------------------------
// Branchless blend (shared by production gs-kernel and diagnostics)
// ---------------------------------------------------------------------------
__device__ __forceinline__ float4 blend4(const float4 v, const float4 m,
                                         const float4 h, const float4 w,
                                         const int sw, const int qf,
                                         const float hm)
{
    float xw0 = sw == 2 ? m.z : sw == 1 ? m.w : sw == 0 ? v.x : sw == -1 ? v.y : v.z;
    float xw1 = sw == 2 ? m.w : sw == 1 ? v.x : sw == 0 ? v.y : sw == -1 ? v.z : v.w;
    float xw2 = sw == 2 ? v.x : sw == 1 ? v.y : sw == 0 ? v.z : sw == -1 ? v.w : m.x;
    float xw3 = sw == 2 ? v.y : sw == 1 ? v.z : sw == 0 ? v.w : sw == -1 ? m.x : m.y;
    xw0 = ((unsigned)(qf + 0 - sw) < WW) ? xw0 : 0.f;
    xw1 = ((unsigned)(qf + 1 - sw) < WW) ? xw1 : 0.f;
    xw2 = ((unsigned)(qf + 2 - sw) < WW) ? xw2 : 0.f;
    xw3 = ((unsigned)(qf + 3 - sw) < WW) ? xw3 : 0.f;
    float4 o;
    o.x = xw0 + w.x * (hm * h.x - xw0);
    o.y = xw1 + w.y * (hm * h.y - xw1);
    o.z = xw2 + w.z * (hm * h.z - xw2);
    o.w = xw3 + w.w * (hm * h.w - xw3);
    return o;
}

// ---------------------------------------------------------------------------
// Kernel 3 (production, round-12 version — passing): grid-stride, forced MLP
// ---------------------------------------------------------------------------
__global__ __launch_bounds__(256, 1) void k_shift_blend_gs(
        const float* __restrict__ x,
        const int* __restrict__ sh_arr, const int* __restrict__ sw_arr,
        float* __restrict__ out)
{
    const int gtid = blockIdx.x * 256 + threadIdx.x;

    int pack_h = 0, pack_w = 0;
#pragma unroll
    for (int k = 0; k < NGRP; ++k) {
        pack_h |= (sh_arr[k] + 2) << (3 * k);
        pack_w |= (sw_arr[k] + 2) << (3 * k);
    }

#pragma unroll
    for (int half = 0; half < 2; ++half) {
        float4 av[5], mv[5], hv[5], wv[5];
        int   fi[5], swv[5], qfv[5];
        float hmv[5];

#pragma unroll
        for (int u = 0; u < 5; ++u) {
            const int i4 = gtid + (half * 5 + u) * GSSTRIDE;
            const int p4 = i4 & 1023;
            const int pl = i4 >> 10;
            const int b  = pl / CHAN;
            const int c  = pl - b * CHAN;
            const int g  = c >> 6;
            const int r  = p4 >> 4;
            const int qf = (p4 & 15) << 2;
            const int f  = i4 << 2;
            const int ps = pl << 12;

            const int sh = ((pack_h >> (3 * g)) & 7) - 2;
            const int sw = ((pack_w >> (3 * g)) & 7) - 2;

            const int rs  = r - sh;
            hmv[u] = ((unsigned)rs < HH) ? 1.f : 0.f;
            const int rsc = rs < 0 ? 0 : (rs > HH - 1 ? HH - 1 : rs);

            const int mlo = (f - 4 < ps) ? ps : f - 4;
            const int mhi = (f + 4 > ps + PLANE - 4) ? ps + PLANE - 4 : f + 4;
            const int mo  = (sw > 0) ? mlo : mhi;

            fi[u] = f; swv[u] = sw; qfv[u] = qf;
            av[u] = *(const float4*)(x + f);
            mv[u] = *(const float4*)(x + mo);
            hv[u] = *(const float4*)(x + ps + rsc * WW + qf);
            wv[u] = *(const float4*)(g_w0 + (b << 12) + p4 * 4);
        }

        asm volatile("" ::: "memory");

#pragma unroll
        for (int u = 0; u < 5; ++u) {
            const float4 o = blend4(av[u], mv[u], hv[u], wv[u], swv[u], qfv[u], hmv[u]);
            *(float4*)(out + fi[u]) = o;
        }
    }
}

// ===========================================================================
// DIAGNOSTICS (8 passes each -> all land in rocprof top-5 WITH counters;
// write only to d_ws; removed once the ablation question is answered).
// All use the k3 1280-block shape: 16-channel loop, same addresses as prod.
// ===========================================================================
struct K3Geom {
    int base, moff, hoff, qf, sw;
    float hm;
    const float* pb;
    float* ob;
    float4 wv;
};

__device__ __forceinline__ K3Geom k3geom(const float* __restrict__ x,
                                         float* __restrict__ ws,
                                         const int* sh_arr, const int* sw_arr)
{
    K3Geom gm;
    const int tid  = threadIdx.x;
    const int lane = tid & 63;
    const int csub = tid >> 6;
    const int bid  = blockIdx.x;
    const int s    = bid & 15;
    const int g    = (bid >> 4) % NGRP;
    const int b    = bid / (NGRP * 16);
    const int sh   = sh_arr[g];
    gm.sw          = sw_arr[g];

    const int p4   = s * 64 + lane;
    const int r    = p4 >> 4;
    gm.qf          = (p4 & 15) * 4;
    gm.base        = r * WW + gm.qf;
    const int rs   = r - sh;
    gm.hm          = ((unsigned)rs < HH) ? 1.f : 0.f;
    const int rsc  = rs < 0 ? 0 : (rs > HH - 1 ? HH - 1 : rs);
    gm.hoff        = rsc * WW + gm.qf;
    gm.moff        = gm.sw > 0 ? (gm.base - 4 < 0 ? 0 : gm.base - 4)
                               : (gm.base + 4 > PLANE - 4 ? PLANE - 4 : gm.base + 4);
    const int c0   = g * CG + csub * 16;
    gm.pb = x  + ((size_t)b * CHAN + c0) * PLANE;
    gm.ob = ws + ((size_t)b * CHAN + c0) * PLANE;
    gm.wv = *(const float4*)(g_w0 + ((size_t)b << 12) + gm.base);
    return gm;
}

// D4ref: 1R+1W pure copy
__global__ __launch_bounds__(256) void k_e0_copy(
        const float* __restrict__ x, const int* __restrict__ sh_arr,
        const int* __restrict__ sw_arr, float* __restrict__ ws)
{
    K3Geom gm = k3geom(x, ws, sh_arr, sw_arr);
    for (int pass = 0; pass < PASSES; ++pass) {
        const float* p = gm.pb; float* o = gm.ob;
#pragma unroll
        for (int i = 0; i < 16; ++i) {
            *(float4*)(o + gm.base) = *(const float4*)(p + gm.base);
            p += PLANE; o += PLANE;
        }
        asm volatile("" ::: "memory");
    }
}

// E1: 1R+1W + full blend VALU chain (m=h=a, w=const) -> dependency-chain test
__global__ __launch_bounds__(256) void k_e1_valu(
        const float* __restrict__ x, const int* __restrict__ sh_arr,
        const int* __restrict__ sw_arr, float* __restrict__ ws)
{
    K3Geom gm = k3geom(x, ws, sh_arr, sw_arr);
    const float4 wc = make_float4(0.5f, 0.5f, 0.5f, 0.5f);
    for (int pass = 0; pass < PASSES; ++pass) {
        const float* p = gm.pb; float* o = gm.ob;
#pragma unroll
        for (int i = 0; i < 16; ++i) {
            const float4 a = *(const float4*)(p + gm.base);
            *(float4*)(o + gm.base) = blend4(a, a, a, wc, gm.sw, gm.qf, gm.hm);
            p += PLANE; o += PLANE;
        }
        asm volatile("" ::: "memory");
    }
}

// E3: 2R (a + neighbor m) + 1W + blend
__global__ __launch_bounds__(256) void k_e3_am(
        const float* __restrict__ x, const int* __restrict__ sh_arr,
        const int* __restrict__ sw_arr, float* __restrict__ ws)
{
    K3Geom gm = k3geom(x, ws, sh_arr, sw_arr);
    for (int pass = 0; pass < PASSES; ++pass) {
        const float* p = gm.pb; float* o = gm.ob;
#pragma unroll
        for (int i = 0; i < 16; ++i) {
            const float4 a = *(const float4*)(p + gm.base);
            const float4 m = *(const float4*)(p + gm.moff);
            *(float4*)(o + gm.base) = blend4(a, m, a, gm.wv, gm.sw, gm.qf, gm.hm);
            p += PLANE; o += PLANE;
        }
        asm volatile("" ::: "memory");
    }
}

// E4: 2R (a + row-shift h) + 1W + blend
__global__ __launch_bounds__(256) void k_e4_ah(
        const float* __restrict__ x, const int* __restrict__ sh_arr,
        const int* __restrict__ sw_arr, float* __restrict__ ws)
{
    K3Geom gm = k3geom(x, ws, sh_arr, sw_arr);
    for (int pass = 0; pass < PASSES; ++pass) {
        const float* p = gm.pb; float* o = gm.ob;
#pragma unroll
        for (int i = 0; i < 16; ++i) {
            const float4 a = *(const float4*)(p + gm.base);
            const float4 h = *(const float4*)(p + gm.hoff);
            *(float4*)(o + gm.base) = blend4(a, a, h, gm.wv, gm.sw, gm.qf, gm.hm);
            p += PLANE; o += PLANE;
        }
        asm volatile("" ::: "memory");
    }
}

// E2: 3R+1W + blend = exact round-10 production body (against ws)
__global__ __launch_bounds__(256) void k_e2_full(
        const float* __restrict__ x, const int* __restrict__ sh_arr,
        const int* __restrict__ sw_arr, float* __restrict__ ws)
{
    K3Geom gm = k3geom(x, ws, sh_arr, sw_arr);
    for (int pass = 0; pass < PASSES; ++pass) {
        const float* p = gm.pb; float* o = gm.ob;
#pragma unroll
        for (int i = 0; i < 16; ++i) {
            const float4 a = *(const float4*)(p + gm.base);
            const float4 m = *(const float4*)(p + gm.moff);
            const float4 h = *(const float4*)(p + gm.hoff);
            *(float4*)(o + gm.base) = blend4(a, m, h, gm.wv, gm.sw, gm.qf, gm.hm);
            p += PLANE; o += PLANE;
        }
        asm volatile("" ::: "memory");
    }
}

extern "C" void kernel_launch(void* const* d_in, const int* in_sizes, int n_in,
                              void* d_out, int out_size, void* d_ws, size_t ws_size,
                              hipStream_t stream)
{
    const float* x   = (const float*)d_in[0];
    const float* eg  = (const float*)d_in[1];
    const float* w1  = (const float*)d_in[2];
    const float* b1  = (const float*)d_in[3];
    const float* w2  = (const float*)d_in[4];
    const float* b2  = (const float*)d_in[5];
    const int*   shh = (const int*)d_in[6];
    const int*   shw = (const int*)d_in[7];
    float* out = (float*)d_out;

    // production pipeline (correctness)
    k_reduce_mean<<<BATCH * HH, 256, 0, stream>>>(eg);
    k_conv_dir<<<BATCH * 16, 256, 0, stream>>>(w1, b1, w2, b2);
    k_shift_blend_gs<<<GSBLK, 256, 0, stream>>>(x, shh, shw, out);

    // ablation diagnostics (one round; ws-only)
    if (ws_size >= (size_t)96 * 1024 * 1024) {
        float* ws = (float*)d_ws;
        const int k3grid = BATCH * NGRP * 16;
        k_e0_copy<<<k3grid, 256, 0, stream>>>(x, shh, shw, ws);
        k_e1_valu<<<k3grid, 256, 0, stream>>>(x, shh, shw, ws);
        k_e3_am  <<<k3grid, 256, 0, stream>>>(x, shh, shw, ws);
        k_e4_ah  <<<k3grid, 256, 0, stream>>>(x, shh, shw, ws);
        k_e2_full<<<k3grid, 256, 0, stream>>>(x, shh, shw, ws);
    }
}

// Round 14
// 80.804 us; speedup vs baseline: 11.1204x; 11.1204x over previous
//
#include <hip/hip_runtime.h>

// Problem constants: B=16, C=320, H=W=64, G=5, Cg=64
#define BATCH 16
#define CHAN  320
#define HH    64
#define WW    64
#define PLANE (HH*WW)            // 4096
#define NGRP  5
#define CG    64

__device__ float g_em[BATCH * PLANE];   // channel SUM of edge_guidance
__device__ float g_w0[BATCH * PLANE];   // softmax weight for the H-shift term

// ---------------------------------------------------------------------------
// Kernel 1: channel-sum of edge_guidance
// ---------------------------------------------------------------------------
__global__ void k_reduce_mean(const float* __restrict__ eg)
{
    __shared__ float red[256];
    const int bid = blockIdx.x;
    const int b = bid >> 6;
    const int r = bid & 63;
    const int q   = threadIdx.x & 63;
    const int grp = threadIdx.x >> 6;

    const float* p = eg + (((size_t)b * CHAN + (size_t)grp * 80) * PLANE) + r * WW + q;
    float s = 0.f;
#pragma unroll 8
    for (int c = 0; c < 80; ++c)
        s += p[(size_t)c * PLANE];

    red[threadIdx.x] = s;
    __syncthreads();
    if (grp == 0) {
        g_em[(size_t)bid * 64 + q] = red[q] + red[q + 64] + red[q + 128] + red[q + 192];
    }
}

// ---------------------------------------------------------------------------
// Kernel 2: conv1+relu -> conv2 -> softmax -> w0
// ---------------------------------------------------------------------------
__global__ void k_conv_dir(const float* __restrict__ w1, const float* __restrict__ b1,
                           const float* __restrict__ w2, const float* __restrict__ b2)
{
    __shared__ float sem[20][20];
    __shared__ float shh[18][18];
    __shared__ float sw1[16][9];
    __shared__ float sb1[16];
    __shared__ float sw2[2][16][9];
    __shared__ float sb2[2];

    const int bid = blockIdx.x;
    const int b  = bid >> 4;
    const int t  = bid & 15;
    const int r0 = (t >> 2) * 16;
    const int q0 = (t & 3) * 16;
    const int tid = threadIdx.x;

    if (tid < 144) sw1[tid / 9][tid % 9] = w1[tid];
    if (tid < 16)  sb1[tid] = b1[tid];
    for (int i = tid; i < 288; i += 256) ((float*)sw2)[i] = w2[i];
    if (tid < 2)   sb2[tid] = b2[tid];

    const float scale = 1.0f / (float)CHAN;
    for (int i = tid; i < 400; i += 256) {
        const int lr = i / 20, lq = i % 20;
        const int r = r0 + lr - 2, q = q0 + lq - 2;
        float v = 0.f;
        if ((unsigned)r < HH && (unsigned)q < WW)
            v = g_em[((size_t)b * HH + r) * WW + q] * scale;
        sem[lr][lq] = v;
    }
    __syncthreads();

    const int lr = tid >> 4;
    const int lq = tid & 15;
    float l0 = sb2[0];
    float l1 = sb2[1];

    for (int i = 0; i < 16; ++i) {
        for (int p = tid; p < 324; p += 256) {
            const int hr = p / 18, hq = p % 18;
            const int gr = r0 - 1 + hr, gq = q0 - 1 + hq;
            float acc = 0.f;
            if ((unsigned)gr < HH && (unsigned)gq < WW) {
                acc = sb1[i];
#pragma unroll
                for (int dr = 0; dr < 3; ++dr)
#pragma unroll
                    for (int dq = 0; dq < 3; ++dq)
                        acc += sem[hr + dr][hq + dq] * sw1[i][dr * 3 + dq];
                acc = fmaxf(acc, 0.f);
            }
            shh[hr][hq] = acc;
        }
        __syncthreads();
#pragma unroll
        for (int dr = 0; dr < 3; ++dr)
#pragma unroll
            for (int dq = 0; dq < 3; ++dq) {
                const float hv = shh[lr + dr][lq + dq];
                l0 += hv * sw2[0][i][dr * 3 + dq];
                l1 += hv * sw2[1][i][dr * 3 + dq];
            }
        __syncthreads();
    }

    const float m  = fmaxf(l0, l1);
    const float e0 = expf(l0 - m);
    const float e1 = expf(l1 - m);
    const float w0v = e0 / (e0 + e1);
    g_w0[((size_t)b * HH + (r0 + lr)) * WW + (q0 + lq)] = w0v;
}

// ---------------------------------------------------------------------------
// Branchless blend (verbatim from the fast-compiling e2 diagnostic)
// ---------------------------------------------------------------------------
__device__ __forceinline__ float4 blend4(const float4 v, const float4 m,
                                         const float4 h, const float4 w,
                                         const int sw, const int qf,
                                         const float hm)
{
    float xw0 = sw == 2 ? m.z : sw == 1 ? m.w : sw == 0 ? v.x : sw == -1 ? v.y : v.z;
    float xw1 = sw == 2 ? m.w : sw == 1 ? v.x : sw == 0 ? v.y : sw == -1 ? v.z : v.w;
    float xw2 = sw == 2 ? v.x : sw == 1 ? v.y : sw == 0 ? v.z : sw == -1 ? v.w : m.x;
    float xw3 = sw == 2 ? v.y : sw == 1 ? v.z : sw == 0 ? v.w : sw == -1 ? m.x : m.y;
    xw0 = ((unsigned)(qf + 0 - sw) < WW) ? xw0 : 0.f;
    xw1 = ((unsigned)(qf + 1 - sw) < WW) ? xw1 : 0.f;
    xw2 = ((unsigned)(qf + 2 - sw) < WW) ? xw2 : 0.f;
    xw3 = ((unsigned)(qf + 3 - sw) < WW) ? xw3 : 0.f;
    float4 o;
    o.x = xw0 + w.x * (hm * h.x - xw0);
    o.y = xw1 + w.y * (hm * h.y - xw1);
    o.z = xw2 + w.z * (hm * h.z - xw2);
    o.w = xw3 + w.w * (hm * h.w - xw3);
    return o;
}

// ---------------------------------------------------------------------------
// Geometry precompute (verbatim from e2; single instantiation, runtime sw)
// ---------------------------------------------------------------------------
struct K3Geom {
    int base, moff, hoff, qf, sw;
    float hm;
    const float* pb;
    float* ob;
    float4 wv;
};

__device__ __forceinline__ K3Geom k3geom(const float* __restrict__ x,
                                         float* __restrict__ outp,
                                         const int* sh_arr, const int* sw_arr)
{
    K3Geom gm;
    const int tid  = threadIdx.x;
    const int lane = tid & 63;
    const int csub = tid >> 6;
    const int bid  = blockIdx.x;
    const int s    = bid & 15;
    const int g    = (bid >> 4) % NGRP;
    const int b    = bid / (NGRP * 16);
    const int sh   = sh_arr[g];
    gm.sw          = sw_arr[g];

    const int p4   = s * 64 + lane;
    const int r    = p4 >> 4;
    gm.qf          = (p4 & 15) * 4;
    gm.base        = r * WW + gm.qf;
    const int rs   = r - sh;
    gm.hm          = ((unsigned)rs < HH) ? 1.f : 0.f;
    const int rsc  = rs < 0 ? 0 : (rs > HH - 1 ? HH - 1 : rs);
    gm.hoff        = rsc * WW + gm.qf;
    gm.moff        = gm.sw > 0 ? (gm.base - 4 < 0 ? 0 : gm.base - 4)
                               : (gm.base + 4 > PLANE - 4 ? PLANE - 4 : gm.base + 4);
    const int c0   = g * CG + csub * 16;
    gm.pb = x    + ((size_t)b * CHAN + c0) * PLANE;
    gm.ob = outp + ((size_t)b * CHAN + c0) * PLANE;
    gm.wv = *(const float4*)(g_w0 + ((size_t)b << 12) + gm.base);
    return gm;
}

// ---------------------------------------------------------------------------
// Kernel 3 (production) = k_e2_full verbatim, store target = out, npass
// runtime arg (=1). Round-13 measured: VGPR=136 (pipelined schedule, all
// 48 loads of the unrolled body in flight), 24.9 us/pass — 2x every prior
// production variant (~50 us, VGPR=36, serial schedule). Loop structure
// kept EXACTLY as the fast compilation (incl. trailing asm barrier).
// ---------------------------------------------------------------------------
__global__ __launch_bounds__(256) void k_shift_blend(
        const float* __restrict__ x, const int* __restrict__ sh_arr,
        const int* __restrict__ sw_arr, float* __restrict__ out, int npass)
{
    K3Geom gm = k3geom(x, out, sh_arr, sw_arr);
    for (int pass = 0; pass < npass; ++pass) {
        const float* p = gm.pb; float* o = gm.ob;
#pragma unroll
        for (int i = 0; i < 16; ++i) {
            const float4 a = *(const float4*)(p + gm.base);
            const float4 m = *(const float4*)(p + gm.moff);
            const float4 h = *(const float4*)(p + gm.hoff);
            *(float4*)(o + gm.base) = blend4(a, m, h, gm.wv, gm.sw, gm.qf, gm.hm);
            p += PLANE; o += PLANE;
        }
        asm volatile("" ::: "memory");
    }
}

extern "C" void kernel_launch(void* const* d_in, const int* in_sizes, int n_in,
                              void* d_out, int out_size, void* d_ws, size_t ws_size,
                              hipStream_t stream)
{
    const float* x   = (const float*)d_in[0];
    const float* eg  = (const float*)d_in[1];
    const float* w1  = (const float*)d_in[2];
    const float* b1  = (const float*)d_in[3];
    const float* w2  = (const float*)d_in[4];
    const float* b2  = (const float*)d_in[5];
    const int*   shh = (const int*)d_in[6];
    const int*   shw = (const int*)d_in[7];
    float* out = (float*)d_out;

    k_reduce_mean<<<BATCH * HH, 256, 0, stream>>>(eg);
    k_conv_dir<<<BATCH * 16, 256, 0, stream>>>(w1, b1, w2, b2);
    k_shift_blend<<<BATCH * NGRP * 16, 256, 0, stream>>>(x, shh, shw, out, 1);
}

// Round 15
// 61.107 us; speedup vs baseline: 14.7049x; 1.3223x over previous
//
#include <hip/hip_runtime.h>

// Problem constants: B=16, C=320, H=W=64, G=5, Cg=64
#define BATCH 16
#define CHAN  320
#define HH    64
#define WW    64
#define PLANE (HH*WW)            // 4096
#define NGRP  5
#define CG    64
#define NTOT  ((size_t)BATCH * CHAN * PLANE)   // 20.97M floats
#define N4    ((int)(NTOT / 4))                // 5,242,880 float4
#define GSBLK 2048
#define GSSTRIDE (GSBLK * 256)                 // 524288 -> exactly 10 iters

__device__ float g_em[BATCH * PLANE];   // channel SUM of edge_guidance
__device__ float g_w0[BATCH * PLANE];   // softmax weight for the H-shift term

// ---------------------------------------------------------------------------
// Kernel 1: channel-sum of edge_guidance
// ---------------------------------------------------------------------------
__global__ void k_reduce_mean(const float* __restrict__ eg)
{
    __shared__ float red[256];
    const int bid = blockIdx.x;
    const int b = bid >> 6;
    const int r = bid & 63;
    const int q   = threadIdx.x & 63;
    const int grp = threadIdx.x >> 6;

    const float* p = eg + (((size_t)b * CHAN + (size_t)grp * 80) * PLANE) + r * WW + q;
    float s = 0.f;
#pragma unroll 8
    for (int c = 0; c < 80; ++c)
        s += p[(size_t)c * PLANE];

    red[threadIdx.x] = s;
    __syncthreads();
    if (grp == 0) {
        g_em[(size_t)bid * 64 + q] = red[q] + red[q + 64] + red[q + 128] + red[q + 192];
    }
}

// ---------------------------------------------------------------------------
// Kernel 2: conv1+relu -> conv2 -> softmax -> w0
// ---------------------------------------------------------------------------
__global__ void k_conv_dir(const float* __restrict__ w1, const float* __restrict__ b1,
                           const float* __restrict__ w2, const float* __restrict__ b2)
{
    __shared__ float sem[20][20];
    __shared__ float shh[18][18];
    __shared__ float sw1[16][9];
    __shared__ float sb1[16];
    __shared__ float sw2[2][16][9];
    __shared__ float sb2[2];

    const int bid = blockIdx.x;
    const int b  = bid >> 4;
    const int t  = bid & 15;
    const int r0 = (t >> 2) * 16;
    const int q0 = (t & 3) * 16;
    const int tid = threadIdx.x;

    if (tid < 144) sw1[tid / 9][tid % 9] = w1[tid];
    if (tid < 16)  sb1[tid] = b1[tid];
    for (int i = tid; i < 288; i += 256) ((float*)sw2)[i] = w2[i];
    if (tid < 2)   sb2[tid] = b2[tid];

    const float scale = 1.0f / (float)CHAN;
    for (int i = tid; i < 400; i += 256) {
        const int lr = i / 20, lq = i % 20;
        const int r = r0 + lr - 2, q = q0 + lq - 2;
        float v = 0.f;
        if ((unsigned)r < HH && (unsigned)q < WW)
            v = g_em[((size_t)b * HH + r) * WW + q] * scale;
        sem[lr][lq] = v;
    }
    __syncthreads();

    const int lr = tid >> 4;
    const int lq = tid & 15;
    float l0 = sb2[0];
    float l1 = sb2[1];

    for (int i = 0; i < 16; ++i) {
        for (int p = tid; p < 324; p += 256) {
            const int hr = p / 18, hq = p % 18;
            const int gr = r0 - 1 + hr, gq = q0 - 1 + hq;
            float acc = 0.f;
            if ((unsigned)gr < HH && (unsigned)gq < WW) {
                acc = sb1[i];
#pragma unroll
                for (int dr = 0; dr < 3; ++dr)
#pragma unroll
                    for (int dq = 0; dq < 3; ++dq)
                        acc += sem[hr + dr][hq + dq] * sw1[i][dr * 3 + dq];
                acc = fmaxf(acc, 0.f);
            }
            shh[hr][hq] = acc;
        }
        __syncthreads();
#pragma unroll
        for (int dr = 0; dr < 3; ++dr)
#pragma unroll
            for (int dq = 0; dq < 3; ++dq) {
                const float hv = shh[lr + dr][lq + dq];
                l0 += hv * sw2[0][i][dr * 3 + dq];
                l1 += hv * sw2[1][i][dr * 3 + dq];
            }
        __syncthreads();
    }

    const float m  = fmaxf(l0, l1);
    const float e0 = expf(l0 - m);
    const float e1 = expf(l1 - m);
    const float w0v = e0 / (e0 + e1);
    g_w0[((size_t)b * HH + (r0 + lr)) * WW + (q0 + lq)] = w0v;
}

// ---------------------------------------------------------------------------
// Kernel 3 v10: D1-clone grid-stride (2048 blocks, 10 iters/thread), the
// W-shift neighbor comes from the adjacent LANE via __shfl (no 3rd load
// stream, no clamped address): every component consumed from a wrapped or
// row-crossing shfl is one the edge masks zero (checked per sw case).
// Per iter: 2 global reads (a, h) + w0 (L2-hot) + 1 store + ~20 VALU.
// No forced phases / launch_bounds minimum / pass loop -- the natural
// compiler schedule at low VGPR + high occupancy is what made D1 hit
// 6.4 TB/s; both forced-deep-MLP (136 VGPR, 10% occ) and serial (36 VGPR)
// lost on single cold passes.
// ---------------------------------------------------------------------------
__global__ __launch_bounds__(256) void k_shift_blend(
        const float* __restrict__ x, const int* __restrict__ sh_arr,
        const int* __restrict__ sw_arr, float* __restrict__ out)
{
    const int gtid = blockIdx.x * 256 + threadIdx.x;
    const int lane = threadIdx.x & 63;

    int pack_h = 0, pack_w = 0;
#pragma unroll
    for (int k = 0; k < NGRP; ++k) {
        pack_h |= (sh_arr[k] + 2) << (3 * k);
        pack_w |= (sw_arr[k] + 2) << (3 * k);
    }

    for (int i4 = gtid; i4 < N4; i4 += GSSTRIDE) {
        const int p4 = i4 & 1023;          // float4 idx within plane
        const int pl = i4 >> 10;           // plane = b*CHAN + c
        const int b  = pl / CHAN;
        const int c  = pl - b * CHAN;
        const int g  = c >> 6;
        const int r  = p4 >> 4;
        const int qf = (p4 & 15) << 2;
        const int f  = i4 << 2;            // global float index
        const int ps = pl << 12;           // plane start (floats)

        const int sh = ((pack_h >> (3 * g)) & 7) - 2;
        const int sw = ((pack_w >> (3 * g)) & 7) - 2;

        // loads (2 x-streams + w0)
        const float4 a = *(const float4*)(x + f);
        const int rs  = r - sh;
        const float hm = ((unsigned)rs < HH) ? 1.f : 0.f;
        const int rsc = rs < 0 ? 0 : (rs > HH - 1 ? HH - 1 : rs);
        const float4 h = *(const float4*)(x + ps + rsc * WW + qf);
        const float4 w = *(const float4*)(g_w0 + (b << 12) + p4 * 4);

        // neighbor float4 from adjacent lane (wave-uniform sw per iteration:
        // 64 consecutive float4s never cross a plane). Wrapped/row-crossing
        // values only feed edge-masked components.
        const int src = (lane + (sw > 0 ? 63 : (sw < 0 ? 1 : 0))) & 63;
        float4 m;
        m.x = __shfl(a.x, src);
        m.y = __shfl(a.y, src);
        m.z = __shfl(a.z, src);
        m.w = __shfl(a.w, src);

        // W-shift component select + edge masks
        float xw0 = sw == 2 ? m.z : sw == 1 ? m.w : sw == 0 ? a.x : sw == -1 ? a.y : a.z;
        float xw1 = sw == 2 ? m.w : sw == 1 ? a.x : sw == 0 ? a.y : sw == -1 ? a.z : a.w;
        float xw2 = sw == 2 ? a.x : sw == 1 ? a.y : sw == 0 ? a.z : sw == -1 ? a.w : m.x;
        float xw3 = sw == 2 ? a.y : sw == 1 ? a.z : sw == 0 ? a.w : sw == -1 ? m.x : m.y;
        xw0 = ((unsigned)(qf + 0 - sw) < WW) ? xw0 : 0.f;
        xw1 = ((unsigned)(qf + 1 - sw) < WW) ? xw1 : 0.f;
        xw2 = ((unsigned)(qf + 2 - sw) < WW) ? xw2 : 0.f;
        xw3 = ((unsigned)(qf + 3 - sw) < WW) ? xw3 : 0.f;

        float4 o;
        o.x = xw0 + w.x * (hm * h.x - xw0);
        o.y = xw1 + w.y * (hm * h.y - xw1);
        o.z = xw2 + w.z * (hm * h.z - xw2);
        o.w = xw3 + w.w * (hm * h.w - xw3);
        *(float4*)(out + f) = o;
    }
}

extern "C" void kernel_launch(void* const* d_in, const int* in_sizes, int n_in,
                              void* d_out, int out_size, void* d_ws, size_t ws_size,
                              hipStream_t stream)
{
    const float* x   = (const float*)d_in[0];
    const float* eg  = (const float*)d_in[1];
    const float* w1  = (const float*)d_in[2];
    const float* b1  = (const float*)d_in[3];
    const float* w2  = (const float*)d_in[4];
    const float* b2  = (const float*)d_in[5];
    const int*   shh = (const int*)d_in[6];
    const int*   shw = (const int*)d_in[7];
    float* out = (float*)d_out;

    k_reduce_mean<<<BATCH * HH, 256, 0, stream>>>(eg);
    k_conv_dir<<<BATCH * 16, 256, 0, stream>>>(w1, b1, w2, b2);
    k_shift_blend<<<GSBLK, 256, 0, stream>>>(x, shh, shw, out);
}

// Round 16
// 61.018 us; speedup vs baseline: 14.7265x; 1.0015x over previous
//
#include <hip/hip_runtime.h>

// Problem constants: B=16, C=320, H=W=64, G=5, Cg=64
#define BATCH 16
#define CHAN  320
#define HH    64
#define WW    64
#define PLANE (HH*WW)            // 4096
#define NGRP  5
#define CG    64
#define NTOT  ((size_t)BATCH * CHAN * PLANE)   // 20.97M floats
#define N4    ((int)(NTOT / 4))                // 5,242,880 float4
#define GSBLK 2048
#define GSSTRIDE (GSBLK * 256)                 // 524288 -> exactly 10 items/thread

__device__ float g_em[BATCH * PLANE];   // channel SUM of edge_guidance
__device__ float g_w0[BATCH * PLANE];   // softmax weight for the H-shift term

// ---------------------------------------------------------------------------
// Kernel 1: channel-sum of edge_guidance
// ---------------------------------------------------------------------------
__global__ void k_reduce_mean(const float* __restrict__ eg)
{
    __shared__ float red[256];
    const int bid = blockIdx.x;
    const int b = bid >> 6;
    const int r = bid & 63;
    const int q   = threadIdx.x & 63;
    const int grp = threadIdx.x >> 6;

    const float* p = eg + (((size_t)b * CHAN + (size_t)grp * 80) * PLANE) + r * WW + q;
    float s = 0.f;
#pragma unroll 8
    for (int c = 0; c < 80; ++c)
        s += p[(size_t)c * PLANE];

    red[threadIdx.x] = s;
    __syncthreads();
    if (grp == 0) {
        g_em[(size_t)bid * 64 + q] = red[q] + red[q + 64] + red[q + 128] + red[q + 192];
    }
}

// ---------------------------------------------------------------------------
// Kernel 2: conv1+relu -> conv2 -> softmax -> w0
// ---------------------------------------------------------------------------
__global__ void k_conv_dir(const float* __restrict__ w1, const float* __restrict__ b1,
                           const float* __restrict__ w2, const float* __restrict__ b2)
{
    __shared__ float sem[20][20];
    __shared__ float shh[18][18];
    __shared__ float sw1[16][9];
    __shared__ float sb1[16];
    __shared__ float sw2[2][16][9];
    __shared__ float sb2[2];

    const int bid = blockIdx.x;
    const int b  = bid >> 4;
    const int t  = bid & 15;
    const int r0 = (t >> 2) * 16;
    const int q0 = (t & 3) * 16;
    const int tid = threadIdx.x;

    if (tid < 144) sw1[tid / 9][tid % 9] = w1[tid];
    if (tid < 16)  sb1[tid] = b1[tid];
    for (int i = tid; i < 288; i += 256) ((float*)sw2)[i] = w2[i];
    if (tid < 2)   sb2[tid] = b2[tid];

    const float scale = 1.0f / (float)CHAN;
    for (int i = tid; i < 400; i += 256) {
        const int lr = i / 20, lq = i % 20;
        const int r = r0 + lr - 2, q = q0 + lq - 2;
        float v = 0.f;
        if ((unsigned)r < HH && (unsigned)q < WW)
            v = g_em[((size_t)b * HH + r) * WW + q] * scale;
        sem[lr][lq] = v;
    }
    __syncthreads();

    const int lr = tid >> 4;
    const int lq = tid & 15;
    float l0 = sb2[0];
    float l1 = sb2[1];

    for (int i = 0; i < 16; ++i) {
        for (int p = tid; p < 324; p += 256) {
            const int hr = p / 18, hq = p % 18;
            const int gr = r0 - 1 + hr, gq = q0 - 1 + hq;
            float acc = 0.f;
            if ((unsigned)gr < HH && (unsigned)gq < WW) {
                acc = sb1[i];
#pragma unroll
                for (int dr = 0; dr < 3; ++dr)
#pragma unroll
                    for (int dq = 0; dq < 3; ++dq)
                        acc += sem[hr + dr][hq + dq] * sw1[i][dr * 3 + dq];
                acc = fmaxf(acc, 0.f);
            }
            shh[hr][hq] = acc;
        }
        __syncthreads();
#pragma unroll
        for (int dr = 0; dr < 3; ++dr)
#pragma unroll
            for (int dq = 0; dq < 3; ++dq) {
                const float hv = shh[lr + dr][lq + dq];
                l0 += hv * sw2[0][i][dr * 3 + dq];
                l1 += hv * sw2[1][i][dr * 3 + dq];
            }
        __syncthreads();
    }

    const float m  = fmaxf(l0, l1);
    const float e0 = expf(l0 - m);
    const float e1 = expf(l1 - m);
    const float w0v = e0 / (e0 + e1);
    g_w0[((size_t)b * HH + (r0 + lr)) * WW + (q0 + lq)] = w0v;
}

// ---------------------------------------------------------------------------
// Kernel 3 v11: round-15 grid-stride shfl kernel with MANUAL 2-WAY MLP.
// 5 unrolled trips; each loads TWO independent work items (6 loads issued
// back-to-back, pinned above the stores by an asm memory barrier), then
// blends + stores both. Rationale: every "natural" compilation serialized
// to 1 iteration in flight (VGPR=16..36, ~50us at any occupancy); the
// forced 12-deep pipeline (VGPR=136, 10% occ) was worse cold (66us). The
// untested sweet spot is MLP=2 at ~40-50% occupancy (copy wins from there).
// ---------------------------------------------------------------------------
struct Item {
    int f, qf, sw;
    float hm;
    float4 a, h, w;
};

__device__ __forceinline__ Item load_item(const float* __restrict__ x,
                                          const int i4,
                                          const int pack_h, const int pack_w)
{
    Item it;
    const int p4 = i4 & 1023;          // float4 idx within plane
    const int pl = i4 >> 10;           // plane = b*CHAN + c
    const int b  = pl / CHAN;
    const int c  = pl - b * CHAN;
    const int g  = c >> 6;
    const int r  = p4 >> 4;
    it.qf = (p4 & 15) << 2;
    it.f  = i4 << 2;                   // global float index
    const int ps = pl << 12;           // plane start (floats)

    const int sh = ((pack_h >> (3 * g)) & 7) - 2;
    it.sw        = ((pack_w >> (3 * g)) & 7) - 2;

    const int rs = r - sh;
    it.hm = ((unsigned)rs < HH) ? 1.f : 0.f;
    const int rsc = rs < 0 ? 0 : (rs > HH - 1 ? HH - 1 : rs);

    it.a = *(const float4*)(x + it.f);
    it.h = *(const float4*)(x + ps + rsc * WW + it.qf);
    it.w = *(const float4*)(g_w0 + (b << 12) + p4 * 4);
    return it;
}

__device__ __forceinline__ float4 finish_item(const Item& it, const int lane)
{
    const int sw = it.sw;
    const int qf = it.qf;
    const float4 a = it.a;

    // neighbor float4 from adjacent lane (sw wave-uniform; wrapped /
    // row-crossing values only feed edge-masked components)
    const int src = (lane + (sw > 0 ? 63 : (sw < 0 ? 1 : 0))) & 63;
    float4 m;
    m.x = __shfl(a.x, src);
    m.y = __shfl(a.y, src);
    m.z = __shfl(a.z, src);
    m.w = __shfl(a.w, src);

    float xw0 = sw == 2 ? m.z : sw == 1 ? m.w : sw == 0 ? a.x : sw == -1 ? a.y : a.z;
    float xw1 = sw == 2 ? m.w : sw == 1 ? a.x : sw == 0 ? a.y : sw == -1 ? a.z : a.w;
    float xw2 = sw == 2 ? a.x : sw == 1 ? a.y : sw == 0 ? a.z : sw == -1 ? a.w : m.x;
    float xw3 = sw == 2 ? a.y : sw == 1 ? a.z : sw == 0 ? a.w : sw == -1 ? m.x : m.y;
    xw0 = ((unsigned)(qf + 0 - sw) < WW) ? xw0 : 0.f;
    xw1 = ((unsigned)(qf + 1 - sw) < WW) ? xw1 : 0.f;
    xw2 = ((unsigned)(qf + 2 - sw) < WW) ? xw2 : 0.f;
    xw3 = ((unsigned)(qf + 3 - sw) < WW) ? xw3 : 0.f;

    const float hm = it.hm;
    const float4 h = it.h, w = it.w;
    float4 o;
    o.x = xw0 + w.x * (hm * h.x - xw0);
    o.y = xw1 + w.y * (hm * h.y - xw1);
    o.z = xw2 + w.z * (hm * h.z - xw2);
    o.w = xw3 + w.w * (hm * h.w - xw3);
    return o;
}

__global__ __launch_bounds__(256) void k_shift_blend(
        const float* __restrict__ x, const int* __restrict__ sh_arr,
        const int* __restrict__ sw_arr, float* __restrict__ out)
{
    const int gtid = blockIdx.x * 256 + threadIdx.x;
    const int lane = threadIdx.x & 63;

    int pack_h = 0, pack_w = 0;
#pragma unroll
    for (int k = 0; k < NGRP; ++k) {
        pack_h |= (sh_arr[k] + 2) << (3 * k);
        pack_w |= (sw_arr[k] + 2) << (3 * k);
    }

#pragma unroll
    for (int u = 0; u < 5; ++u) {
        const Item A = load_item(x, gtid + (2 * u)     * GSSTRIDE, pack_h, pack_w);
        const Item B = load_item(x, gtid + (2 * u + 1) * GSSTRIDE, pack_h, pack_w);

        asm volatile("" ::: "memory");   // 6 loads pinned above the stores

        const float4 oa = finish_item(A, lane);
        const float4 ob = finish_item(B, lane);
        *(float4*)(out + A.f) = oa;
        *(float4*)(out + B.f) = ob;
    }
}

extern "C" void kernel_launch(void* const* d_in, const int* in_sizes, int n_in,
                              void* d_out, int out_size, void* d_ws, size_t ws_size,
                              hipStream_t stream)
{
    const float* x   = (const float*)d_in[0];
    const float* eg  = (const float*)d_in[1];
    const float* w1  = (const float*)d_in[2];
    const float* b1  = (const float*)d_in[3];
    const float* w2  = (const float*)d_in[4];
    const float* b2  = (const float*)d_in[5];
    const int*   shh = (const int*)d_in[6];
    const int*   shw = (const int*)d_in[7];
    float* out = (float*)d_out;

    k_reduce_mean<<<BATCH * HH, 256, 0, stream>>>(eg);
    k_conv_dir<<<BATCH * 16, 256, 0, stream>>>(w1, b1, w2, b2);
    k_shift_blend<<<GSBLK, 256, 0, stream>>>(x, shh, shw, out);
}